// Round 1
// baseline (258.805 us; speedup 1.0000x reference)
//
#include <hip/hip_runtime.h>
#include <hip/hip_bf16.h>
#include <math.h>

// MoBoAligner forward — closed-form O(B*I*J) reformulation.
//
//   val[b,i,j]   = soft_ok ? (dot/256 - log(-log(u)))/temp : -1000
//   S_geq[b,i,k] = LSE_{j>=k} val[b,i,j]                (reverse cum-LSE)
//   lcp[j1,j2]     = val[j1]   - S_geq[j2+1]   (j1>j2)
//   lcp_geq[j1,j2] = S_geq[j1] - S_geq[j2+1]   (j1>j2)
//   g_i[p] = alpha_i[p] - S_geq[i][p+1]  (-inf if p==J-1 or !mel_mask[p])
//   C_i    = prefix cumLSE of g_i
//   alpha_{i+1}[j] = val[i][j-1] + C_i[j-2]    (masked j >= i+1)
//   delta[i][q]    = logaddexp(S_geq[i][q] + C_i[q-1], log(J-q) - 10)
//   expanded[b,j,d] = sum_i exp(delta[b,i,j]) * text[b,i,d]

#define RNG_MODE 0  // 0: threefry partitionable: ctr=(hi,lo)=(0,n), bits=y0^y1
                    // 1: original split-iota: n<h:(n,n+h)->y0 else (n-h,n)->y1
                    // (flip if absmax comes back O(1))

#define B_ 4
#define I_ 64
#define J_ 512
#define D_ 256

#define NEGINF (-INFINITY)

// ---------------- Threefry-2x32-20, key = (0, 42) --------------------------
__device__ __forceinline__ void tf2x32(unsigned int x0, unsigned int x1,
                                       unsigned int& y0, unsigned int& y1) {
  const unsigned int k0 = 0u, k1 = 42u;
  const unsigned int k2 = k0 ^ k1 ^ 0x1BD11BDAu;
  x0 += k0; x1 += k1;
#define TFR(r) { x0 += x1; x1 = (x1 << r) | (x1 >> (32 - r)); x1 ^= x0; }
  TFR(13) TFR(15) TFR(26) TFR(6)   x0 += k1; x1 += k2 + 1u;
  TFR(17) TFR(29) TFR(16) TFR(24)  x0 += k2; x1 += k0 + 2u;
  TFR(13) TFR(15) TFR(26) TFR(6)   x0 += k0; x1 += k1 + 3u;
  TFR(17) TFR(29) TFR(16) TFR(24)  x0 += k1; x1 += k2 + 4u;
  TFR(13) TFR(15) TFR(26) TFR(6)   x0 += k2; x1 += k0 + 5u;
#undef TFR
  y0 = x0; y1 = x1;
}

__device__ __forceinline__ unsigned int rand_bits(unsigned int n) {
#if RNG_MODE == 0
  unsigned int y0, y1;
  tf2x32(0u, n, y0, y1);
  return y0 ^ y1;
#else
  const unsigned int h = (B_ * I_ * J_) / 2;  // 65536
  unsigned int y0, y1;
  if (n < h) { tf2x32(n, n + h, y0, y1); return y0; }
  else       { tf2x32(n - h, n, y0, y1); return y1; }
#endif
}

// log(-log(u)) with u = jax.random.uniform(key(42), ..., 1e-20, 1.0)[n]
__device__ __forceinline__ float gumbel_term(unsigned int n) {
  unsigned int bits = rand_bits(n);
  float f = __uint_as_float((bits >> 9) | 0x3f800000u) - 1.0f;  // [0,1)
  float u = fmaxf(f + 1e-20f, 1e-20f);
  return logf(-logf(u));
}

// ---------------- streaming logsumexp as (max, sum-exp) pairs --------------
struct MS { float m; float s; };

__device__ __forceinline__ MS ms_comb(MS a, MS b) {
  if (b.m == NEGINF) return a;
  if (a.m == NEGINF) return b;
  MS r;
  if (a.m >= b.m) { r.m = a.m; r.s = a.s + b.s * __expf(b.m - a.m); }
  else            { r.m = b.m; r.s = b.s + a.s * __expf(a.m - b.m); }
  return r;
}
__device__ __forceinline__ MS ms_add(MS a, float x) {
  if (x == NEGINF) return a;
  if (a.m == NEGINF) { MS r; r.m = x; r.s = 1.0f; return r; }
  MS r;
  if (a.m >= x) { r.m = a.m; r.s = a.s + __expf(x - a.m); }
  else          { r.m = x;   r.s = 1.0f + a.s * __expf(a.m - x); }
  return r;
}
__device__ __forceinline__ float ms_val(MS a) {
  if (a.m == NEGINF) return NEGINF;
  return a.m + __logf(a.s);
}
__device__ __forceinline__ float logaddexp_f(float a, float b) {
  float m = fmaxf(a, b);
  if (m == NEGINF) return NEGINF;
  return m + __logf(1.0f + __expf(-fabsf(a - b)));
}

// inclusive (m,s) scan across the 64 lanes of one wave
__device__ __forceinline__ MS wave_incl_scan(MS v, int lane) {
  #pragma unroll
  for (int off = 1; off < 64; off <<= 1) {
    float mo = __shfl_up(v.m, off, 64);
    float so = __shfl_up(v.s, off, 64);
    if (lane >= off) { MS o; o.m = mo; o.s = so; v = ms_comb(o, v); }
  }
  return v;
}

// ---------------- mask helpers (bool-bytes vs int32 auto-detect) -----------
__device__ __forceinline__ bool mask_is_byte(const unsigned char* p) {
  const unsigned int* w = (const unsigned int*)p;
  unsigned int orbits = 0;
  #pragma unroll
  for (int k = 0; k < 16; k++) orbits |= w[k];
  return (orbits & 0xFFFFFF00u) != 0u;  // any high byte set -> byte layout
}
__device__ __forceinline__ int mask_get(const unsigned char* p, int idx, bool isbyte) {
  return isbyte ? (p[idx] != 0) : (((const int*)p)[idx] != 0);
}

// ============ Kernel A: val + S_geq per (b,i) row ==========================
__global__ __launch_bounds__(512) void kernelA(
    const float* __restrict__ text, const float* __restrict__ mel,
    const unsigned char* __restrict__ tmask, const unsigned char* __restrict__ mmask,
    const float* __restrict__ tratio,
    float* __restrict__ val, float* __restrict__ sgeq) {
  int bi = blockIdx.x;
  int b = bi >> 6, i = bi & 63;
  int tid = threadIdx.x;

  __shared__ float t_s[D_];
  __shared__ float v_s[J_];
  __shared__ int sh_ilen, sh_tok, sh_mbyte;

  if (tid == 0) {
    bool tbyte = mask_is_byte(tmask);
    int ilen = 0;
    for (int k = 0; k < I_; k++) ilen += mask_get(tmask, b * I_ + k, tbyte);
    sh_ilen = ilen;
    sh_tok = mask_get(tmask, b * I_ + i, tbyte);
    sh_mbyte = mask_is_byte(mmask) ? 1 : 0;
  }
  if (tid < D_) t_s[tid] = text[(size_t)(b * I_ + i) * D_ + tid];
  __syncthreads();

  int j = tid;  // 512 threads = one j each
  const float4* m4 = (const float4*)(mel + (size_t)(b * J_ + j) * D_);
  const float4* t4 = (const float4*)t_s;
  float4 acc; acc.x = acc.y = acc.z = acc.w = 0.0f;
  #pragma unroll 8
  for (int d4 = 0; d4 < D_ / 4; ++d4) {
    float4 a = m4[d4]; float4 t = t4[d4];
    acc.x += a.x * t.x; acc.y += a.y * t.y;
    acc.z += a.z * t.z; acc.w += a.w * t.w;
  }
  float dot = (acc.x + acc.y) + (acc.z + acc.w);

  float temp = 0.1f + 0.9f * tratio[0];
  float gum = gumbel_term((unsigned)((b * I_ + i) * J_ + j));
  float e = (dot * (1.0f / 256.0f) - gum) / temp;
  int mok = mask_get(mmask, b * J_ + j, sh_mbyte != 0);
  int hi = J_ - sh_ilen + i + 1;
  bool ok = (j >= i + 1) && (j <= hi) && mok && sh_tok;
  float v = ok ? e : -1000.0f;
  v_s[j] = v;
  val[(size_t)bi * J_ + j] = v;
  __syncthreads();

  // reverse cumulative LSE by wave 0: p = reversed index, lane l owns p=l*8+e
  if (tid < 64) {
    int l = tid;
    float xs[8];
    MS tot; tot.m = NEGINF; tot.s = 0.0f;
    #pragma unroll
    for (int e = 0; e < 8; e++) {
      int p = l * 8 + e;
      xs[e] = v_s[J_ - 1 - p];
      tot = ms_add(tot, xs[e]);
    }
    MS inc = wave_incl_scan(tot, l);
    MS ex; ex.m = __shfl_up(inc.m, 1, 64); ex.s = __shfl_up(inc.s, 1, 64);
    if (l == 0) { ex.m = NEGINF; ex.s = 0.0f; }
    MS run = ex;
    #pragma unroll
    for (int e = 0; e < 8; e++) {
      int p = l * 8 + e;
      run = ms_add(run, xs[e]);
      sgeq[(size_t)bi * J_ + (J_ - 1 - p)] = ms_val(run);
    }
  }
}

// ============ Kernel B: DP over i + delta rows (1 wave per batch) ==========
__global__ __launch_bounds__(64) void kernelB(
    const float* __restrict__ val, const float* __restrict__ sgeq,
    const unsigned char* __restrict__ mmask,
    float* __restrict__ delta) {
  int b = blockIdx.x;
  int l = threadIdx.x;

  __shared__ float Sg[J_];
  __shared__ float Vb[J_];
  __shared__ float Cb[J_ + 1];  // Cb[0] = -inf; Cb[1+p] = C[p]

  bool mbyte = mask_is_byte(mmask);
  int mok[8];
  float A[8];  // alpha row, element p = l*8+e
  #pragma unroll
  for (int e = 0; e < 8; e++) {
    int p = l * 8 + e;
    mok[e] = mask_get(mmask, b * J_ + p, mbyte);
    A[e] = (p == 0) ? 0.0f : NEGINF;
  }
  if (l == 0) Cb[0] = NEGINF;

  for (int i = 0; i < I_; i++) {
    const float* sr = sgeq + (size_t)(b * I_ + i) * J_;
    const float* vr = val  + (size_t)(b * I_ + i) * J_;
    ((float4*)Sg)[l * 2]     = ((const float4*)sr)[l * 2];
    ((float4*)Sg)[l * 2 + 1] = ((const float4*)sr)[l * 2 + 1];
    ((float4*)Vb)[l * 2]     = ((const float4*)vr)[l * 2];
    ((float4*)Vb)[l * 2 + 1] = ((const float4*)vr)[l * 2 + 1];
    __syncthreads();

    // g + scan
    float gs[8];
    MS tot; tot.m = NEGINF; tot.s = 0.0f;
    #pragma unroll
    for (int e = 0; e < 8; e++) {
      int p = l * 8 + e;
      float gv = NEGINF;
      if (p <= J_ - 2 && mok[e]) gv = A[e] - Sg[p + 1];
      gs[e] = gv;
      tot = ms_add(tot, gv);
    }
    MS inc = wave_incl_scan(tot, l);
    MS ex; ex.m = __shfl_up(inc.m, 1, 64); ex.s = __shfl_up(inc.s, 1, 64);
    if (l == 0) { ex.m = NEGINF; ex.s = 0.0f; }
    MS run = ex;
    #pragma unroll
    for (int e = 0; e < 8; e++) {
      run = ms_add(run, gs[e]);
      Cb[1 + l * 8 + e] = ms_val(run);
    }
    __syncthreads();

    // delta row i:  logaddexp(Sg[q] + C[q-1], log(J-q) - 10)
    float* drow = delta + (size_t)(b * I_ + i) * J_;
    #pragma unroll
    for (int e = 0; e < 8; e++) {
      int q = l * 8 + e;
      float t1 = Sg[q] + Cb[q];
      float t2 = __logf((float)(J_ - q)) - 10.0f;
      drow[q] = logaddexp_f(t1, t2);
    }
    // alpha row i+1:  val[i][j-1] + C[j-2], masked j >= i+1
    if (i < I_ - 1) {
      #pragma unroll
      for (int e = 0; e < 8; e++) {
        int jx = l * 8 + e;
        float na = NEGINF;
        if (jx >= i + 1) na = Vb[jx - 1] + Cb[jx - 1];
        A[e] = na;
      }
    }
    __syncthreads();
  }
}

// ============ Kernel C: expanded[b,j,d] = sum_i exp(delta) * text ==========
__global__ __launch_bounds__(256) void kernelC(
    const float* __restrict__ delta, const float* __restrict__ text,
    float* __restrict__ expanded) {
  int bj = blockIdx.x;
  int b = bj >> 9, j = bj & (J_ - 1);
  int d = threadIdx.x;
  __shared__ float w_s[I_];
  if (d < I_) w_s[d] = expf(delta[(size_t)(b * I_ + d) * J_ + j]);
  __syncthreads();
  float acc = 0.0f;
  #pragma unroll 8
  for (int i = 0; i < I_; i++)
    acc += w_s[i] * text[(size_t)(b * I_ + i) * D_ + d];
  expanded[(size_t)(b * J_ + j) * D_ + d] = acc;
}

extern "C" void kernel_launch(void* const* d_in, const int* in_sizes, int n_in,
                              void* d_out, int out_size, void* d_ws, size_t ws_size,
                              hipStream_t stream) {
  (void)in_sizes; (void)n_in; (void)out_size; (void)ws_size;
  const float* text = (const float*)d_in[0];
  const float* mel  = (const float*)d_in[1];
  const unsigned char* tmask = (const unsigned char*)d_in[2];
  const unsigned char* mmask = (const unsigned char*)d_in[3];
  const float* tratio = (const float*)d_in[4];

  float* out = (float*)d_out;
  float* delta = out;                                  // B*I*J
  float* expanded = out + (size_t)B_ * I_ * J_;        // B*J*D
  float* val  = (float*)d_ws;                          // B*I*J
  float* sgeq = val + (size_t)B_ * I_ * J_;            // B*I*J

  kernelA<<<B_ * I_, 512, 0, stream>>>(text, mel, tmask, mmask, tratio, val, sgeq);
  kernelB<<<B_, 64, 0, stream>>>(val, sgeq, mmask, delta);
  kernelC<<<B_ * J_, 256, 0, stream>>>(delta, text, expanded);
}

// Round 3
// 112.503 us; speedup vs baseline: 2.3004x; 2.3004x over previous
//
#include <hip/hip_runtime.h>
#include <hip/hip_bf16.h>
#include <math.h>

// MoBoAligner forward — closed-form O(B*I*J) reformulation.
//
//   val[b,i,j]   = soft_ok ? (dot/256 - log(-log(u)))/temp : -1000
//   S_geq[b,i,k] = LSE_{j>=k} val[b,i,j]                (reverse cum-LSE)
//   g_i[p] = alpha_i[p] - S_geq[i][p+1]  (empty if p==J-1 or !mel_mask[p])
//   C_i    = prefix cumLSE of g_i        (exact per-prefix max via (m,s) pairs)
//   alpha_{i+1}[j] = val[i][j-1] + C_i[j-2]    (masked j >= i+1)
//   w[i][q]  = exp(S_geq[i][q] + C_i[q-1]) + (J-q)*e^-10   ( = exp(delta) )
//   delta = log(w)   (kernelD);  expanded[b,j,d] = sum_i w * text  (kernelC)

#define B_ 4
#define I_ 64
#define J_ 512
#define D_ 256

#define NEGINF (-INFINITY)
#define SENT (-1.0e30f)   // finite "-inf" sentinel: keeps all arithmetic NaN-free

// ---------------- Threefry-2x32-20, key = (0, 42) --------------------------
__device__ __forceinline__ void tf2x32(unsigned int x0, unsigned int x1,
                                       unsigned int& y0, unsigned int& y1) {
  const unsigned int k0 = 0u, k1 = 42u;
  const unsigned int k2 = k0 ^ k1 ^ 0x1BD11BDAu;
  x0 += k0; x1 += k1;
#define TFR(r) { x0 += x1; x1 = (x1 << r) | (x1 >> (32 - r)); x1 ^= x0; }
  TFR(13) TFR(15) TFR(26) TFR(6)   x0 += k1; x1 += k2 + 1u;
  TFR(17) TFR(29) TFR(16) TFR(24)  x0 += k2; x1 += k0 + 2u;
  TFR(13) TFR(15) TFR(26) TFR(6)   x0 += k0; x1 += k1 + 3u;
  TFR(17) TFR(29) TFR(16) TFR(24)  x0 += k1; x1 += k2 + 4u;
  TFR(13) TFR(15) TFR(26) TFR(6)   x0 += k2; x1 += k0 + 5u;
#undef TFR
  y0 = x0; y1 = x1;
}

__device__ __forceinline__ unsigned int rand_bits(unsigned int n) {
  unsigned int y0, y1;
  tf2x32(0u, n, y0, y1);
  return y0 ^ y1;
}

// log(-log(u)) with u = jax.random.uniform(key(42), ..., 1e-20, 1.0)[n]
__device__ __forceinline__ float gumbel_term(unsigned int n) {
  unsigned int bits = rand_bits(n);
  float f = __uint_as_float((bits >> 9) | 0x3f800000u) - 1.0f;  // [0,1)
  float u = fmaxf(f + 1e-20f, 1e-20f);
  return logf(-logf(u));
}

// ---------------- streaming logsumexp pairs (kernelA, branchy is fine) -----
struct MS { float m; float s; };

__device__ __forceinline__ MS ms_comb(MS a, MS b) {
  if (b.m == NEGINF) return a;
  if (a.m == NEGINF) return b;
  MS r;
  if (a.m >= b.m) { r.m = a.m; r.s = a.s + b.s * __expf(b.m - a.m); }
  else            { r.m = b.m; r.s = b.s + a.s * __expf(a.m - b.m); }
  return r;
}
__device__ __forceinline__ MS ms_add(MS a, float x) {
  if (x == NEGINF) return a;
  if (a.m == NEGINF) { MS r; r.m = x; r.s = 1.0f; return r; }
  MS r;
  if (a.m >= x) { r.m = a.m; r.s = a.s + __expf(x - a.m); }
  else          { r.m = x;   r.s = 1.0f + a.s * __expf(a.m - x); }
  return r;
}
__device__ __forceinline__ float ms_val(MS a) {
  if (a.m == NEGINF) return NEGINF;
  return a.m + __logf(a.s);
}

// inclusive (m,s) scan across the 64 lanes of one wave (kernelA only)
__device__ __forceinline__ MS wave_incl_scan(MS v, int lane) {
  #pragma unroll
  for (int off = 1; off < 64; off <<= 1) {
    float mo = __shfl_up(v.m, off, 64);
    float so = __shfl_up(v.s, off, 64);
    if (lane >= off) { MS o; o.m = mo; o.s = so; v = ms_comb(o, v); }
  }
  return v;
}

// ---------------- branch-free (m,s) state + DPP scan (kernelB) -------------
// state (m, s) represents value m + log(s); (SENT, 0) == empty (-inf).
struct MS2 { float m; float s; };

__device__ __forceinline__ MS2 comb2(MS2 a, MS2 b) {
  MS2 r;
  r.m = fmaxf(a.m, b.m);
  r.s = a.s * __expf(a.m - r.m) + b.s * __expf(b.m - r.m);
  return r;
}

template<int CTRL, int RM, int BM, bool BC>
__device__ __forceinline__ float dppf(float oldv, float src) {
  return __int_as_float(__builtin_amdgcn_update_dpp(
      __float_as_int(oldv), __float_as_int(src), CTRL, RM, BM, BC));
}

// move a state through DPP; invalid/masked lanes yield identity (SENT, 0)
template<int CTRL, int RM>
__device__ __forceinline__ MS2 dpp_ms(MS2 v) {
  MS2 r;
  r.m = dppf<CTRL, RM, 0xf, false>(SENT, v.m);
  r.s = dppf<CTRL, RM, 0xf, false>(0.0f, v.s);
  return r;
}

// inclusive (m,s) scan over 64 lanes: row_shr 1,2,4,8 + row_bcast 15,31
__device__ __forceinline__ MS2 wave_incl_scan_ms2(MS2 v) {
  v = comb2(dpp_ms<0x111, 0xf>(v), v);  // row_shr:1
  v = comb2(dpp_ms<0x112, 0xf>(v), v);  // row_shr:2
  v = comb2(dpp_ms<0x114, 0xf>(v), v);  // row_shr:4
  v = comb2(dpp_ms<0x118, 0xf>(v), v);  // row_shr:8
  v = comb2(dpp_ms<0x142, 0xa>(v), v);  // row_bcast:15 -> rows 1,3
  v = comb2(dpp_ms<0x143, 0xc>(v), v);  // row_bcast:31 -> rows 2,3
  return v;
}

// ---------------- mask helpers (bool-bytes vs int32 auto-detect) -----------
__device__ __forceinline__ bool mask_is_byte(const unsigned char* p) {
  const unsigned int* w = (const unsigned int*)p;
  unsigned int orbits = 0;
  #pragma unroll
  for (int k = 0; k < 16; k++) orbits |= w[k];
  return (orbits & 0xFFFFFF00u) != 0u;  // any high byte set -> byte layout
}
__device__ __forceinline__ int mask_get(const unsigned char* p, int idx, bool isbyte) {
  return isbyte ? (p[idx] != 0) : (((const int*)p)[idx] != 0);
}

// ============ Kernel A: val + S_geq per (b,i) row ==========================
__global__ __launch_bounds__(512) void kernelA(
    const float* __restrict__ text, const float* __restrict__ mel,
    const unsigned char* __restrict__ tmask, const unsigned char* __restrict__ mmask,
    const float* __restrict__ tratio,
    float* __restrict__ val, float* __restrict__ sgeq) {
  int bi = blockIdx.x;
  int b = bi >> 6, i = bi & 63;
  int tid = threadIdx.x;

  __shared__ float t_s[D_];
  __shared__ float v_s[J_];
  __shared__ int sh_ilen, sh_tok, sh_mbyte;

  if (tid == 0) {
    bool tbyte = mask_is_byte(tmask);
    int ilen = 0;
    for (int k = 0; k < I_; k++) ilen += mask_get(tmask, b * I_ + k, tbyte);
    sh_ilen = ilen;
    sh_tok = mask_get(tmask, b * I_ + i, tbyte);
    sh_mbyte = mask_is_byte(mmask) ? 1 : 0;
  }
  if (tid < D_) t_s[tid] = text[(size_t)(b * I_ + i) * D_ + tid];
  __syncthreads();

  int j = tid;  // 512 threads = one j each
  const float4* m4 = (const float4*)(mel + (size_t)(b * J_ + j) * D_);
  const float4* t4 = (const float4*)t_s;
  float4 acc; acc.x = acc.y = acc.z = acc.w = 0.0f;
  #pragma unroll 8
  for (int d4 = 0; d4 < D_ / 4; ++d4) {
    float4 a = m4[d4]; float4 t = t4[d4];
    acc.x += a.x * t.x; acc.y += a.y * t.y;
    acc.z += a.z * t.z; acc.w += a.w * t.w;
  }
  float dot = (acc.x + acc.y) + (acc.z + acc.w);

  float temp = 0.1f + 0.9f * tratio[0];
  float gum = gumbel_term((unsigned)((b * I_ + i) * J_ + j));
  float e = (dot * (1.0f / 256.0f) - gum) / temp;
  int mok = mask_get(mmask, b * J_ + j, sh_mbyte != 0);
  int hi = J_ - sh_ilen + i + 1;
  bool ok = (j >= i + 1) && (j <= hi) && mok && sh_tok;
  float v = ok ? e : -1000.0f;
  v_s[j] = v;
  val[(size_t)bi * J_ + j] = v;
  __syncthreads();

  // reverse cumulative LSE by wave 0: p = reversed index, lane l owns p=l*8+e
  if (tid < 64) {
    int l = tid;
    float xs[8];
    MS tot; tot.m = NEGINF; tot.s = 0.0f;
    #pragma unroll
    for (int e = 0; e < 8; e++) {
      int p = l * 8 + e;
      xs[e] = v_s[J_ - 1 - p];
      tot = ms_add(tot, xs[e]);
    }
    MS inc = wave_incl_scan(tot, l);
    MS ex; ex.m = __shfl_up(inc.m, 1, 64); ex.s = __shfl_up(inc.s, 1, 64);
    if (l == 0) { ex.m = NEGINF; ex.s = 0.0f; }
    MS run = ex;
    #pragma unroll
    for (int e = 0; e < 8; e++) {
      int p = l * 8 + e;
      run = ms_add(run, xs[e]);
      sgeq[(size_t)bi * J_ + (J_ - 1 - p)] = ms_val(run);
    }
  }
}

// ============ Kernel B: DP over i, register-resident, (m,s) DPP scans ======
// 1 wave per batch. Blocked layout: lane l owns elements p = l*8 + e.
// No LDS, no barriers, no +/-inf anywhere (SENT sentinel keeps NaN out).
__global__ __launch_bounds__(64) void kernelB(
    const float* __restrict__ val, const float* __restrict__ sgeq,
    const unsigned char* __restrict__ mmask,
    float* __restrict__ wrow) {
  const int b = blockIdx.x;
  const int l = threadIdx.x;

  const bool mbyte = mask_is_byte(mmask);
  bool gok[8];
  float floorc[8], A[8];
#pragma unroll
  for (int e = 0; e < 8; e++) {
    int p = l * 8 + e;
    gok[e] = (p <= J_ - 2) && (mask_get(mmask, b * J_ + p, mbyte) != 0);
    floorc[e] = (float)(J_ - p) * 4.5399929762484854e-05f;  // (J-q)*e^-10
    A[e] = (p == 0) ? 0.0f : SENT;
  }

  const float4* sb4 = (const float4*)(sgeq + (size_t)b * I_ * J_);
  const float4* vb4 = (const float4*)(val  + (size_t)b * I_ * J_);
  float* wbase = wrow + (size_t)b * I_ * J_;

  // current row registers (8 floats each, as 2 float4)
  float4 Sq0 = sb4[l * 2], Sq1 = sb4[l * 2 + 1];
  float4 Vq0 = vb4[l * 2], Vq1 = vb4[l * 2 + 1];

  for (int i = 0; i < I_; i++) {
    // prefetch next row (clamped; redundant reload on last iter is harmless)
    const int rn = (i + 1 < I_) ? i + 1 : i;
    const int ro = rn * (J_ / 4);
    float4 Sn0 = sb4[ro + l * 2], Sn1 = sb4[ro + l * 2 + 1];
    float4 Vn0 = vb4[ro + l * 2], Vn1 = vb4[ro + l * 2 + 1];

    float S[8] = {Sq0.x, Sq0.y, Sq0.z, Sq0.w, Sq1.x, Sq1.y, Sq1.z, Sq1.w};
    float V[8] = {Vq0.x, Vq0.y, Vq0.z, Vq0.w, Vq1.x, Vq1.y, Vq1.z, Vq1.w};

    // g[p] = alpha[p] - S[p+1] (or SENT); e=7 needs next lane's S[0]
    float nextS0 = dppf<0x130, 0xf, 0xf, false>(0.0f, S[0]);  // wave_shl:1
    MS2 st[8];
#pragma unroll
    for (int e = 0; e < 8; e++) {
      float sp1 = (e < 7) ? S[e + 1] : nextS0;
      st[e].m = gok[e] ? (A[e] - sp1) : SENT;
      st[e].s = 1.0f;
    }

    // in-lane inclusive (m,s) Kogge-Stone over 8 elements (depth 3, ILP-wide)
    MS2 t1[8], t2[8], t3[8];
#pragma unroll
    for (int e = 0; e < 8; e++) t1[e] = (e >= 1) ? comb2(st[e - 1], st[e]) : st[e];
#pragma unroll
    for (int e = 0; e < 8; e++) t2[e] = (e >= 2) ? comb2(t1[e - 2], t1[e]) : t1[e];
#pragma unroll
    for (int e = 0; e < 8; e++) t3[e] = (e >= 4) ? comb2(t2[e - 4], t2[e]) : t2[e];

    // wave-level scan of lane totals; exclusive via wave_shr:1
    // (lane 0's invalid source returns old=(SENT,0) = empty, no fixup needed)
    MS2 incl = wave_incl_scan_ms2(t3[7]);
    MS2 excl = dpp_ms<0x138, 0xf>(incl);  // wave_shr:1

    // C[e] = LSE over prefix [0..l*8+e]
    float C[8];
#pragma unroll
    for (int e = 0; e < 8; e++) {
      MS2 cs = comb2(excl, t3[e]);
      C[e] = cs.m + __logf(cs.s);
    }

    float prevC7 = dppf<0x138, 0xf, 0xf, false>(SENT, C[7]);  // C[-1] at lane0

    // w row: exp(S[q] + C[q-1]) + (J-q)e^-10
    float wo[8];
#pragma unroll
    for (int e = 0; e < 8; e++) {
      float cm1 = (e >= 1) ? C[e - 1] : prevC7;
      wo[e] = __expf(S[e] + cm1) + floorc[e];
    }
    float4* wout4 = (float4*)(wbase + (size_t)i * J_);
    wout4[l * 2]     = make_float4(wo[0], wo[1], wo[2], wo[3]);
    wout4[l * 2 + 1] = make_float4(wo[4], wo[5], wo[6], wo[7]);

    // alpha_{i+1}[j] = V[j-1] + C[j-2], masked j >= i+1
    if (i < I_ - 1) {
      float prevC6 = dppf<0x138, 0xf, 0xf, false>(SENT, C[6]);
      float prevV7 = dppf<0x138, 0xf, 0xf, false>(SENT, V[7]);
#pragma unroll
      for (int e = 0; e < 8; e++) {
        int j = l * 8 + e;
        float vjm1 = (e >= 1) ? V[e - 1] : prevV7;
        float cjm2 = (e >= 2) ? C[e - 2] : ((e == 1) ? prevC7 : prevC6);
        float na = vjm1 + cjm2;
        A[e] = (j >= i + 1) ? na : SENT;
      }
    }
    Sq0 = Sn0; Sq1 = Sn1; Vq0 = Vn0; Vq1 = Vn1;
  }
}

// ============ Kernel D: delta = log(w), elementwise ========================
__global__ __launch_bounds__(256) void kernelD(
    const float* __restrict__ w, float* __restrict__ delta) {
  int n = blockIdx.x * 256 + threadIdx.x;
  delta[n] = __logf(w[n]);
}

// ============ Kernel C: expanded[b,j,d] = sum_i w * text ===================
__global__ __launch_bounds__(256) void kernelC(
    const float* __restrict__ wrow, const float* __restrict__ text,
    float* __restrict__ expanded) {
  int bj = blockIdx.x;
  int b = bj >> 9, j = bj & (J_ - 1);
  int d = threadIdx.x;
  __shared__ float w_s[I_];
  if (d < I_) w_s[d] = wrow[(size_t)(b * I_ + d) * J_ + j];
  __syncthreads();
  float acc = 0.0f;
  #pragma unroll 8
  for (int i = 0; i < I_; i++)
    acc += w_s[i] * text[(size_t)(b * I_ + i) * D_ + d];
  expanded[(size_t)(b * J_ + j) * D_ + d] = acc;
}

extern "C" void kernel_launch(void* const* d_in, const int* in_sizes, int n_in,
                              void* d_out, int out_size, void* d_ws, size_t ws_size,
                              hipStream_t stream) {
  (void)in_sizes; (void)n_in; (void)out_size; (void)ws_size;
  const float* text = (const float*)d_in[0];
  const float* mel  = (const float*)d_in[1];
  const unsigned char* tmask = (const unsigned char*)d_in[2];
  const unsigned char* mmask = (const unsigned char*)d_in[3];
  const float* tratio = (const float*)d_in[4];

  float* out = (float*)d_out;
  float* delta = out;                                  // B*I*J
  float* expanded = out + (size_t)B_ * I_ * J_;        // B*J*D
  float* val  = (float*)d_ws;                          // B*I*J
  float* sgeq = val + (size_t)B_ * I_ * J_;            // B*I*J
  float* wrow = sgeq + (size_t)B_ * I_ * J_;           // B*I*J

  kernelA<<<B_ * I_, 512, 0, stream>>>(text, mel, tmask, mmask, tratio, val, sgeq);
  kernelB<<<B_, 64, 0, stream>>>(val, sgeq, mmask, wrow);
  kernelD<<<(B_ * I_ * J_) / 256, 256, 0, stream>>>(wrow, delta);
  kernelC<<<B_ * J_, 256, 0, stream>>>(wrow, text, expanded);
}

// Round 4
// 85.455 us; speedup vs baseline: 3.0286x; 1.3165x over previous
//
#include <hip/hip_runtime.h>
#include <hip/hip_bf16.h>
#include <math.h>

// MoBoAligner forward — closed-form O(B*I*J) reformulation.
//
//   val[b,i,j]   = soft_ok ? (dot/256 - log(-log(u)))/temp : -1000
//   S_geq[b,i,k] = LSE_{j>=k} val[b,i,j]                (reverse cum-LSE)
//   g_i[p] = alpha_i[p] - S_geq[i][p+1]  (empty if p==J-1 or !mel_mask[p])
//   C_i    = prefix cumLSE of g_i        (exact per-prefix max via (m,s) pairs)
//   alpha_{i+1}[j] = val[i][j-1] + C_i[j-2]    (masked j >= i+1)
//   w[i][q]  = exp(S_geq[i][q] + C_i[q-1]) + (J-q)*e^-10   ( = exp(delta) )
//   delta = log(w)   (kernelD);  expanded[b,j,d] = sum_i w * text  (kernelC)
//
// kernelB carries alpha and all scan state as (m,s) pairs -> no v_log at all;
// comb2 uses the single-exp form (exp(-|dm|) + selects), Sklansky-12 in-lane.

#define B_ 4
#define I_ 64
#define J_ 512
#define D_ 256

#define NEGINF (-INFINITY)
#define SENT (-1.0e30f)   // finite "-inf" sentinel: keeps all arithmetic NaN-free

// ---------------- Threefry-2x32-20, key = (0, 42) --------------------------
__device__ __forceinline__ void tf2x32(unsigned int x0, unsigned int x1,
                                       unsigned int& y0, unsigned int& y1) {
  const unsigned int k0 = 0u, k1 = 42u;
  const unsigned int k2 = k0 ^ k1 ^ 0x1BD11BDAu;
  x0 += k0; x1 += k1;
#define TFR(r) { x0 += x1; x1 = (x1 << r) | (x1 >> (32 - r)); x1 ^= x0; }
  TFR(13) TFR(15) TFR(26) TFR(6)   x0 += k1; x1 += k2 + 1u;
  TFR(17) TFR(29) TFR(16) TFR(24)  x0 += k2; x1 += k0 + 2u;
  TFR(13) TFR(15) TFR(26) TFR(6)   x0 += k0; x1 += k1 + 3u;
  TFR(17) TFR(29) TFR(16) TFR(24)  x0 += k1; x1 += k2 + 4u;
  TFR(13) TFR(15) TFR(26) TFR(6)   x0 += k2; x1 += k0 + 5u;
#undef TFR
  y0 = x0; y1 = x1;
}

__device__ __forceinline__ unsigned int rand_bits(unsigned int n) {
  unsigned int y0, y1;
  tf2x32(0u, n, y0, y1);
  return y0 ^ y1;
}

// log(-log(u)) with u = jax.random.uniform(key(42), ..., 1e-20, 1.0)[n]
__device__ __forceinline__ float gumbel_term(unsigned int n) {
  unsigned int bits = rand_bits(n);
  float f = __uint_as_float((bits >> 9) | 0x3f800000u) - 1.0f;  // [0,1)
  float u = fmaxf(f + 1e-20f, 1e-20f);
  return logf(-logf(u));
}

// ---------------- streaming logsumexp pairs (kernelA, branchy is fine) -----
struct MS { float m; float s; };

__device__ __forceinline__ MS ms_comb(MS a, MS b) {
  if (b.m == NEGINF) return a;
  if (a.m == NEGINF) return b;
  MS r;
  if (a.m >= b.m) { r.m = a.m; r.s = a.s + b.s * __expf(b.m - a.m); }
  else            { r.m = b.m; r.s = b.s + a.s * __expf(a.m - b.m); }
  return r;
}
__device__ __forceinline__ MS ms_add(MS a, float x) {
  if (x == NEGINF) return a;
  if (a.m == NEGINF) { MS r; r.m = x; r.s = 1.0f; return r; }
  MS r;
  if (a.m >= x) { r.m = a.m; r.s = a.s + __expf(x - a.m); }
  else          { r.m = x;   r.s = 1.0f + a.s * __expf(a.m - x); }
  return r;
}
__device__ __forceinline__ float ms_val(MS a) {
  if (a.m == NEGINF) return NEGINF;
  return a.m + __logf(a.s);
}

// inclusive (m,s) scan across the 64 lanes of one wave (kernelA only)
__device__ __forceinline__ MS wave_incl_scan(MS v, int lane) {
  #pragma unroll
  for (int off = 1; off < 64; off <<= 1) {
    float mo = __shfl_up(v.m, off, 64);
    float so = __shfl_up(v.s, off, 64);
    if (lane >= off) { MS o; o.m = mo; o.s = so; v = ms_comb(o, v); }
  }
  return v;
}

// ---------------- branch-free (m,s) state, single-exp combine (kernelB) ----
// state (m, s) represents value m + log(s); (SENT, 0) == empty (-inf).
struct MS2 { float m; float s; };

__device__ __forceinline__ MS2 comb2(MS2 a, MS2 b) {
  MS2 r;
  float d = a.m - b.m;
  r.m = fmaxf(a.m, b.m);
  float e = __expf(-fabsf(d));          // exp(-|dm|), one transcendental
  float sbig   = (d >= 0.0f) ? a.s : b.s;
  float ssmall = (d >= 0.0f) ? b.s : a.s;
  r.s = fmaf(ssmall, e, sbig);
  return r;
}

template<int CTRL, int RM, int BM, bool BC>
__device__ __forceinline__ float dppf(float oldv, float src) {
  return __int_as_float(__builtin_amdgcn_update_dpp(
      __float_as_int(oldv), __float_as_int(src), CTRL, RM, BM, BC));
}

// move a state through DPP; invalid/masked lanes yield identity (SENT, 0)
template<int CTRL, int RM>
__device__ __forceinline__ MS2 dpp_ms(MS2 v) {
  MS2 r;
  r.m = dppf<CTRL, RM, 0xf, false>(SENT, v.m);
  r.s = dppf<CTRL, RM, 0xf, false>(0.0f, v.s);
  return r;
}

// inclusive (m,s) scan over 64 lanes: row_shr 1,2,4,8 + row_bcast 15,31
__device__ __forceinline__ MS2 wave_incl_scan_ms2(MS2 v) {
  v = comb2(dpp_ms<0x111, 0xf>(v), v);  // row_shr:1
  v = comb2(dpp_ms<0x112, 0xf>(v), v);  // row_shr:2
  v = comb2(dpp_ms<0x114, 0xf>(v), v);  // row_shr:4
  v = comb2(dpp_ms<0x118, 0xf>(v), v);  // row_shr:8
  v = comb2(dpp_ms<0x142, 0xa>(v), v);  // row_bcast:15 -> rows 1,3
  v = comb2(dpp_ms<0x143, 0xc>(v), v);  // row_bcast:31 -> rows 2,3
  return v;
}

// ---------------- mask helpers (bool-bytes vs int32 auto-detect) -----------
__device__ __forceinline__ bool mask_is_byte(const unsigned char* p) {
  const unsigned int* w = (const unsigned int*)p;
  unsigned int orbits = 0;
  #pragma unroll
  for (int k = 0; k < 16; k++) orbits |= w[k];
  return (orbits & 0xFFFFFF00u) != 0u;  // any high byte set -> byte layout
}
__device__ __forceinline__ int mask_get(const unsigned char* p, int idx, bool isbyte) {
  return isbyte ? (p[idx] != 0) : (((const int*)p)[idx] != 0);
}

// ============ Kernel A: val + S_geq per (b,i) row ==========================
__global__ __launch_bounds__(512) void kernelA(
    const float* __restrict__ text, const float* __restrict__ mel,
    const unsigned char* __restrict__ tmask, const unsigned char* __restrict__ mmask,
    const float* __restrict__ tratio,
    float* __restrict__ val, float* __restrict__ sgeq) {
  int bi = blockIdx.x;
  int b = bi >> 6, i = bi & 63;
  int tid = threadIdx.x;

  __shared__ float t_s[D_];
  __shared__ float v_s[J_];
  __shared__ int sh_ilen, sh_tok, sh_mbyte;

  if (tid == 0) {
    bool tbyte = mask_is_byte(tmask);
    int ilen = 0;
    for (int k = 0; k < I_; k++) ilen += mask_get(tmask, b * I_ + k, tbyte);
    sh_ilen = ilen;
    sh_tok = mask_get(tmask, b * I_ + i, tbyte);
    sh_mbyte = mask_is_byte(mmask) ? 1 : 0;
  }
  if (tid < D_) t_s[tid] = text[(size_t)(b * I_ + i) * D_ + tid];
  __syncthreads();

  int j = tid;  // 512 threads = one j each
  const float4* m4 = (const float4*)(mel + (size_t)(b * J_ + j) * D_);
  const float4* t4 = (const float4*)t_s;
  float4 acc; acc.x = acc.y = acc.z = acc.w = 0.0f;
  #pragma unroll 8
  for (int d4 = 0; d4 < D_ / 4; ++d4) {
    float4 a = m4[d4]; float4 t = t4[d4];
    acc.x += a.x * t.x; acc.y += a.y * t.y;
    acc.z += a.z * t.z; acc.w += a.w * t.w;
  }
  float dot = (acc.x + acc.y) + (acc.z + acc.w);

  float temp = 0.1f + 0.9f * tratio[0];
  float gum = gumbel_term((unsigned)((b * I_ + i) * J_ + j));
  float e = (dot * (1.0f / 256.0f) - gum) / temp;
  int mok = mask_get(mmask, b * J_ + j, sh_mbyte != 0);
  int hi = J_ - sh_ilen + i + 1;
  bool ok = (j >= i + 1) && (j <= hi) && mok && sh_tok;
  float v = ok ? e : -1000.0f;
  v_s[j] = v;
  val[(size_t)bi * J_ + j] = v;
  __syncthreads();

  // reverse cumulative LSE by wave 0: p = reversed index, lane l owns p=l*8+e
  if (tid < 64) {
    int l = tid;
    float xs[8];
    MS tot; tot.m = NEGINF; tot.s = 0.0f;
    #pragma unroll
    for (int e = 0; e < 8; e++) {
      int p = l * 8 + e;
      xs[e] = v_s[J_ - 1 - p];
      tot = ms_add(tot, xs[e]);
    }
    MS inc = wave_incl_scan(tot, l);
    MS ex; ex.m = __shfl_up(inc.m, 1, 64); ex.s = __shfl_up(inc.s, 1, 64);
    if (l == 0) { ex.m = NEGINF; ex.s = 0.0f; }
    MS run = ex;
    #pragma unroll
    for (int e = 0; e < 8; e++) {
      int p = l * 8 + e;
      run = ms_add(run, xs[e]);
      sgeq[(size_t)bi * J_ + (J_ - 1 - p)] = ms_val(run);
    }
  }
}

// ============ Kernel B: DP over i, register-resident, pair-carried alpha ===
// 1 wave per batch. Blocked layout: lane l owns elements p = l*8 + e.
// No LDS, no barriers, no logs; Sklansky-12 in-lane + 6-step wave scan.
__global__ __launch_bounds__(64) void kernelB(
    const float* __restrict__ val, const float* __restrict__ sgeq,
    const unsigned char* __restrict__ mmask,
    float* __restrict__ wrow) {
  const int b = blockIdx.x;
  const int l = threadIdx.x;

  const bool mbyte = mask_is_byte(mmask);
  bool gok[8];
  float floorc[8];
  float Am[8], As[8];  // alpha as (m,s) pair: value = Am + log(As)
#pragma unroll
  for (int e = 0; e < 8; e++) {
    int p = l * 8 + e;
    gok[e] = (p <= J_ - 2) && (mask_get(mmask, b * J_ + p, mbyte) != 0);
    floorc[e] = (float)(J_ - p) * 4.5399929762484854e-05f;  // (J-q)*e^-10
    Am[e] = (p == 0) ? 0.0f : SENT;
    As[e] = (p == 0) ? 1.0f : 0.0f;
  }

  const float4* sb4 = (const float4*)(sgeq + (size_t)b * I_ * J_);
  const float4* vb4 = (const float4*)(val  + (size_t)b * I_ * J_);
  float* wbase = wrow + (size_t)b * I_ * J_;

  // current row registers (8 floats each, as 2 float4)
  float4 Sq0 = sb4[l * 2], Sq1 = sb4[l * 2 + 1];
  float4 Vq0 = vb4[l * 2], Vq1 = vb4[l * 2 + 1];

  for (int i = 0; i < I_; i++) {
    // prefetch next row (clamped; redundant reload on last iter is harmless)
    const int rn = (i + 1 < I_) ? i + 1 : i;
    const int ro = rn * (J_ / 4);
    float4 Sn0 = sb4[ro + l * 2], Sn1 = sb4[ro + l * 2 + 1];
    float4 Vn0 = vb4[ro + l * 2], Vn1 = vb4[ro + l * 2 + 1];

    float S[8] = {Sq0.x, Sq0.y, Sq0.z, Sq0.w, Sq1.x, Sq1.y, Sq1.z, Sq1.w};
    float V[8] = {Vq0.x, Vq0.y, Vq0.z, Vq0.w, Vq1.x, Vq1.y, Vq1.z, Vq1.w};

    // g[p] = alpha[p] - S[p+1] as pair (Am - S[p+1], As); e=7 needs next
    // lane's S[0] (wave_shl:1; lane63 invalid -> masked by gok anyway)
    float nextS0 = dppf<0x130, 0xf, 0xf, false>(0.0f, S[0]);
    MS2 st[8];
#pragma unroll
    for (int e = 0; e < 8; e++) {
      float sp1 = (e < 7) ? S[e + 1] : nextS0;
      st[e].m = gok[e] ? (Am[e] - sp1) : SENT;
      st[e].s = gok[e] ? As[e] : 0.0f;
    }

    // in-lane inclusive Sklansky scan over 8 elements (12 comb2, depth 3)
    MS2 t1[8], t2[8], t3[8];
    t1[0] = st[0];                 t1[1] = comb2(st[0], st[1]);
    t1[2] = st[2];                 t1[3] = comb2(st[2], st[3]);
    t1[4] = st[4];                 t1[5] = comb2(st[4], st[5]);
    t1[6] = st[6];                 t1[7] = comb2(st[6], st[7]);
    t2[0] = t1[0]; t2[1] = t1[1];
    t2[2] = comb2(t1[1], t1[2]);   t2[3] = comb2(t1[1], t1[3]);
    t2[4] = t1[4]; t2[5] = t1[5];
    t2[6] = comb2(t1[5], t1[6]);   t2[7] = comb2(t1[5], t1[7]);
    t3[0] = t2[0]; t3[1] = t2[1]; t3[2] = t2[2]; t3[3] = t2[3];
    t3[4] = comb2(t2[3], t2[4]);   t3[5] = comb2(t2[3], t2[5]);
    t3[6] = comb2(t2[3], t2[6]);   t3[7] = comb2(t2[3], t2[7]);

    // wave-level scan of lane totals; exclusive via wave_shr:1
    MS2 incl = wave_incl_scan_ms2(t3[7]);
    MS2 wexcl = dpp_ms<0x138, 0xf>(incl);  // lane0 -> identity (SENT,0)

    // EX[e] = exclusive prefix at p = l*8+e  (= C[p-1] as a pair)
    MS2 EX[8];
    EX[0] = wexcl;
#pragma unroll
    for (int e = 1; e < 8; e++) EX[e] = comb2(wexcl, t3[e - 1]);

    // w[q] = exp(S[q] + C[q-1]) + floor = exp(S+EX.m)*EX.s + floor (no log!)
    float wo[8];
#pragma unroll
    for (int e = 0; e < 8; e++)
      wo[e] = fmaf(__expf(S[e] + EX[e].m), EX[e].s, floorc[e]);
    float4* wout4 = (float4*)(wbase + (size_t)i * J_);
    wout4[l * 2]     = make_float4(wo[0], wo[1], wo[2], wo[3]);
    wout4[l * 2 + 1] = make_float4(wo[4], wo[5], wo[6], wo[7]);

    // alpha_{i+1}[j] = V[j-1] + C[j-2]  -> pair (V[j-1] + EX[j-1].m, EX[j-1].s)
    // (EX[j-1] = exclusive at j-1 = inclusive at j-2); masked j >= i+1
    if (i < I_ - 1) {
      float prevV7  = dppf<0x138, 0xf, 0xf, false>(SENT, V[7]);
      float prevEm7 = dppf<0x138, 0xf, 0xf, false>(SENT, EX[7].m);
      float prevEs7 = dppf<0x138, 0xf, 0xf, false>(0.0f, EX[7].s);
#pragma unroll
      for (int e = 0; e < 8; e++) {
        int j = l * 8 + e;
        float vjm1 = (e >= 1) ? V[e - 1] : prevV7;
        float em   = (e >= 1) ? EX[e - 1].m : prevEm7;
        float es   = (e >= 1) ? EX[e - 1].s : prevEs7;
        bool live = (j >= i + 1);
        Am[e] = live ? (vjm1 + em) : SENT;
        As[e] = live ? es : 0.0f;
      }
    }
    Sq0 = Sn0; Sq1 = Sn1; Vq0 = Vn0; Vq1 = Vn1;
  }
}

// ============ Kernel D: delta = log(w), elementwise ========================
__global__ __launch_bounds__(256) void kernelD(
    const float* __restrict__ w, float* __restrict__ delta) {
  int n = blockIdx.x * 256 + threadIdx.x;
  delta[n] = __logf(w[n]);
}

// ============ Kernel C: expanded[b,j,d] = sum_i w * text ===================
__global__ __launch_bounds__(256) void kernelC(
    const float* __restrict__ wrow, const float* __restrict__ text,
    float* __restrict__ expanded) {
  int bj = blockIdx.x;
  int b = bj >> 9, j = bj & (J_ - 1);
  int d = threadIdx.x;
  __shared__ float w_s[I_];
  if (d < I_) w_s[d] = wrow[(size_t)(b * I_ + d) * J_ + j];
  __syncthreads();
  float acc = 0.0f;
  #pragma unroll 8
  for (int i = 0; i < I_; i++)
    acc += w_s[i] * text[(size_t)(b * I_ + i) * D_ + d];
  expanded[(size_t)(b * J_ + j) * D_ + d] = acc;
}

extern "C" void kernel_launch(void* const* d_in, const int* in_sizes, int n_in,
                              void* d_out, int out_size, void* d_ws, size_t ws_size,
                              hipStream_t stream) {
  (void)in_sizes; (void)n_in; (void)out_size; (void)ws_size;
  const float* text = (const float*)d_in[0];
  const float* mel  = (const float*)d_in[1];
  const unsigned char* tmask = (const unsigned char*)d_in[2];
  const unsigned char* mmask = (const unsigned char*)d_in[3];
  const float* tratio = (const float*)d_in[4];

  float* out = (float*)d_out;
  float* delta = out;                                  // B*I*J
  float* expanded = out + (size_t)B_ * I_ * J_;        // B*J*D
  float* val  = (float*)d_ws;                          // B*I*J
  float* sgeq = val + (size_t)B_ * I_ * J_;            // B*I*J
  float* wrow = sgeq + (size_t)B_ * I_ * J_;           // B*I*J

  kernelA<<<B_ * I_, 512, 0, stream>>>(text, mel, tmask, mmask, tratio, val, sgeq);
  kernelB<<<B_, 64, 0, stream>>>(val, sgeq, mmask, wrow);
  kernelD<<<(B_ * I_ * J_) / 256, 256, 0, stream>>>(wrow, delta);
  kernelC<<<B_ * J_, 256, 0, stream>>>(wrow, text, expanded);
}